// Round 3
// baseline (283.229 us; speedup 1.0000x reference)
//
#include <hip/hip_runtime.h>
#include <stdint.h>

typedef unsigned short u16;
typedef __attribute__((ext_vector_type(8))) __bf16 bf16x8;
typedef __attribute__((ext_vector_type(4))) float f32x4;

__device__ __forceinline__ u16 f2bf(float f) {
    union { float f; uint32_t u; } v; v.f = f;
    uint32_t r = (v.u + 0x7FFFu + ((v.u >> 16) & 1u)) >> 16;
    return (u16)r;
}
__device__ __forceinline__ float bf2f(u16 u) {
    union { uint32_t u; float f; } v; v.u = ((uint32_t)u) << 16;
    return v.f;
}

#define BM 128
#define BN 128
#define BK 32

// C = A * Bt^T, A [M,K] bf16 rm, Bt [N,K] bf16 rm.
// MODE 0: fused QKV projection, N=3072. Section bn>>10: 0->q(b0,o0), 1->k(b1,o1),
//         2->v(b2) written TRANSPOSED [b,e,s] into o2.
// MODE 2: bf16 out * scale into o0 (scores)
// MODE 3: fp32 out into o3 (attn @ v)
// All epilogues: per-wave LDS retile, NO block barriers (in-wave lgkm ordering only).
template<int MODE>
__global__ __launch_bounds__(256, 2) void gemm_bt(
    const u16* __restrict__ A, const u16* __restrict__ Bt,
    const float* __restrict__ b0, const float* __restrict__ b1, const float* __restrict__ b2,
    u16* __restrict__ o0, u16* __restrict__ o1, u16* __restrict__ o2,
    float* __restrict__ o3,
    int M, int N, int K, long sA, long sB, long sC, float scale)
{
    __shared__ __align__(16) u16 smem[BM * BK + BN * BK]; // 16 KB staging
    __shared__ __align__(16) u16 epi[4 * 64 * 72];        // 36 KB per-wave epilogue
    u16* As = smem;
    u16* Bs = smem + BM * BK;

    const int t = threadIdx.x;
    const int lane = t & 63;
    const int wave = t >> 6;
    const int wm = (wave & 1) * 64;
    const int wn = (wave >> 1) * 64;
    const int bm = blockIdx.y * BM;
    const int bn = blockIdx.x * BN;
    const long bz = blockIdx.z;
    const u16* Ab = A + bz * sA;
    const u16* Bb = Bt + bz * sB;

    f32x4 acc[4][4];
#pragma unroll
    for (int i = 0; i < 4; ++i)
#pragma unroll
        for (int j = 0; j < 4; ++j)
            acc[i][j] = (f32x4){0.f, 0.f, 0.f, 0.f};

    const int lrow = t >> 2;
    const int lcol = (t & 3) * 8;

    for (int k0 = 0; k0 < K; k0 += BK) {
#pragma unroll
        for (int r = 0; r < 2; ++r) {
            const u16* ga = Ab + (long)(bm + r * 64 + lrow) * K + (k0 + lcol);
            __builtin_amdgcn_global_load_lds(
                (const __attribute__((address_space(1))) void*)ga,
                (__attribute__((address_space(3))) void*)&As[(r * 256 + t) * 8],
                16, 0, 0);
        }
#pragma unroll
        for (int r = 0; r < 2; ++r) {
            const u16* gb = Bb + (long)(bn + r * 64 + lrow) * K + (k0 + lcol);
            __builtin_amdgcn_global_load_lds(
                (const __attribute__((address_space(1))) void*)gb,
                (__attribute__((address_space(3))) void*)&Bs[(r * 256 + t) * 8],
                16, 0, 0);
        }
        __syncthreads();

        const int fm = lane & 15;
        const int fk = (lane >> 4) * 8;
        bf16x8 af[4], bfr[4];
#pragma unroll
        for (int i = 0; i < 4; ++i) {
            af[i]  = *(const bf16x8*)&As[(wm + i * 16 + fm) * BK + fk];
            bfr[i] = *(const bf16x8*)&Bs[(wn + i * 16 + fm) * BK + fk];
        }
#pragma unroll
        for (int i = 0; i < 4; ++i)
#pragma unroll
            for (int j = 0; j < 4; ++j)
                acc[i][j] = __builtin_amdgcn_mfma_f32_16x16x32_bf16(af[i], bfr[j], acc[i][j], 0, 0, 0);
        __syncthreads();
    }

    // C/D layout: col = lane&15, row = (lane>>4)*4 + reg
    const int cm = (lane >> 4) * 4;
    const int cn = lane & 15;

    if (MODE == 3) {
        // ---- fp32 out, per-wave retile, 2 passes of 32 rows ----
        float* Ew = (float*)epi + wave * (32 * 68);
#pragma unroll
        for (int p2 = 0; p2 < 2; ++p2) {
#pragma unroll
            for (int ii = 0; ii < 2; ++ii) {
                const int i = p2 * 2 + ii;
#pragma unroll
                for (int j = 0; j < 4; ++j)
#pragma unroll
                    for (int r = 0; r < 4; ++r)
                        Ew[(ii * 16 + cm + r) * 68 + j * 16 + cn] = acc[i][j][r];
            }
#pragma unroll
            for (int it = 0; it < 8; ++it) {
                const int row = it * 4 + (lane >> 4);
                const int c4 = (lane & 15) * 4;
                const f32x4 w = *(const f32x4*)&Ew[row * 68 + c4];
                const int gm = bm + wm + p2 * 32 + row;
                *(f32x4*)&o3[bz * sC + (long)gm * N + bn + wn + c4] = w;
            }
        }
    } else if (MODE == 0 && (bn >> 10) == 2) {
        // ---- v projection: transposed [b,e,s], per-wave retile ----
        u16* Ew = epi + wave * (64 * 72);
        float bb[4];
#pragma unroll
        for (int j = 0; j < 4; ++j) bb[j] = b2[(bn & 1023) + wn + j * 16 + cn];
#pragma unroll
        for (int i = 0; i < 4; ++i)
#pragma unroll
            for (int j = 0; j < 4; ++j) {
                ushort4 pk;
                pk.x = f2bf(acc[i][j][0] + bb[j]);
                pk.y = f2bf(acc[i][j][1] + bb[j]);
                pk.z = f2bf(acc[i][j][2] + bb[j]);
                pk.w = f2bf(acc[i][j][3] + bb[j]);
                *(ushort4*)&Ew[(j * 16 + cn) * 72 + i * 16 + cm] = pk; // [e][s]
            }
        const int bgi = (bm + wm) >> 11;
        const int sbase = (bm + wm) & 2047;
#pragma unroll
        for (int it = 0; it < 8; ++it) {
            const int e = it * 8 + (lane >> 3);
            const int s8 = (lane & 7) * 8;
            const uint4 w = *(const uint4*)&Ew[e * 72 + s8];
            const int eg = (bn & 1023) + wn + e;
            *(uint4*)&o2[((((long)bgi << 10) + eg) << 11) + sbase + s8] = w;
        }
    } else {
        // ---- row-major bf16 (q, k, scores), per-wave retile ----
        u16* C;
        int Nout, ncol0;
        long cbase;
        const float* bias;
        if (MODE == 2) {
            C = o0; Nout = N; ncol0 = bn; cbase = bz * sC; bias = nullptr;
        } else {
            const int sec = bn >> 10;
            C = sec ? o1 : o0; Nout = 1024; ncol0 = bn & 1023; cbase = 0;
            bias = sec ? b1 : b0;
        }
        float bb[4];
#pragma unroll
        for (int j = 0; j < 4; ++j)
            bb[j] = bias ? bias[ncol0 + wn + j * 16 + cn] : 0.f;
        u16* Ew = epi + wave * (64 * 72);
#pragma unroll
        for (int i = 0; i < 4; ++i)
#pragma unroll
            for (int j = 0; j < 4; ++j) {
                const int col = j * 16 + cn;
#pragma unroll
                for (int r = 0; r < 4; ++r) {
                    float v = acc[i][j][r];
                    v = (MODE == 2) ? v * scale : v + bb[j];
                    Ew[(i * 16 + cm + r) * 72 + col] = f2bf(v);
                }
            }
#pragma unroll
        for (int it = 0; it < 8; ++it) {
            const int row = it * 8 + (lane >> 3);
            const int c8 = (lane & 7) * 8;
            const uint4 w = *(const uint4*)&Ew[row * 72 + c8];
            const int gm = bm + wm + row;
            *(uint4*)&C[cbase + (long)gm * Nout + ncol0 + wn + c8] = w;
        }
    }
}

// fp32 -> bf16 converts: blocks [0,8192) -> x, then 1024 each for Wq/Wk/Wv
__global__ __launch_bounds__(256) void cvt_all(
    const float* __restrict__ x, const float* __restrict__ wq,
    const float* __restrict__ wk, const float* __restrict__ wv,
    u16* __restrict__ xb, u16* __restrict__ wb)
{
    const int b = blockIdx.x;
    const float* src; u16* dst; long base;
    if (b < 8192)       { src = x;  dst = xb;             base = (long)b * 1024; }
    else if (b < 9216)  { src = wq; dst = wb;             base = (long)(b - 8192) * 1024; }
    else if (b < 10240) { src = wk; dst = wb + (1 << 20); base = (long)(b - 9216) * 1024; }
    else                { src = wv; dst = wb + (2 << 20); base = (long)(b - 10240) * 1024; }
    const long i = base + threadIdx.x * 4;
    const f32x4 f = *(const f32x4*)(src + i);
    ushort4 o;
    o.x = f2bf(f[0]); o.y = f2bf(f[1]); o.z = f2bf(f[2]); o.w = f2bf(f[3]);
    *(ushort4*)(dst + i) = o;
}

// One block per row, 256 threads, 2048 cols, in-place bf16 softmax.
__global__ __launch_bounds__(256) void softmax_rows(u16* __restrict__ S) {
    const long base = (long)blockIdx.x * 2048;
    const int t = threadIdx.x;
    const int lane = t & 63, wave = t >> 6;
    __shared__ float red[4];
    float v[8];
    float m = -3.0e38f;
#pragma unroll
    for (int i = 0; i < 8; ++i) {
        v[i] = bf2f(S[base + t + i * 256]);
        m = fmaxf(m, v[i]);
    }
#pragma unroll
    for (int off = 32; off > 0; off >>= 1) m = fmaxf(m, __shfl_down(m, off));
    if (lane == 0) red[wave] = m;
    __syncthreads();
    m = fmaxf(fmaxf(red[0], red[1]), fmaxf(red[2], red[3]));
    __syncthreads();
    float sum = 0.f;
#pragma unroll
    for (int i = 0; i < 8; ++i) { v[i] = __expf(v[i] - m); sum += v[i]; }
#pragma unroll
    for (int off = 32; off > 0; off >>= 1) sum += __shfl_down(sum, off);
    if (lane == 0) red[wave] = sum;
    __syncthreads();
    sum = red[0] + red[1] + red[2] + red[3];
    const float inv = 1.0f / sum;
#pragma unroll
    for (int i = 0; i < 8; ++i) S[base + t + i * 256] = f2bf(v[i] * inv);
}

extern "C" void kernel_launch(void* const* d_in, const int* in_sizes, int n_in,
                              void* d_out, int out_size, void* d_ws, size_t ws_size,
                              hipStream_t stream) {
    const float* x  = (const float*)d_in[0];
    const float* Wq = (const float*)d_in[1];
    const float* bq = (const float*)d_in[2];
    const float* Wk = (const float*)d_in[3];
    const float* bk = (const float*)d_in[4];
    const float* Wv = (const float*)d_in[5];
    const float* bv = (const float*)d_in[6];
    float* out = (float*)d_out;

    const int B = 4, S = 2048, D = 1024, E = 1024;
    const int M = B * S; // 8192

    u16* xb  = (u16*)d_ws;                       // [M,D]
    u16* wb  = xb  + (size_t)M * D;              // [3E,D] concat Wq,Wk,Wv
    u16* qb  = wb  + (size_t)3 * E * D;          // [M,E]
    u16* kb  = qb  + (size_t)M * E;              // [M,E]
    u16* vbT = kb  + (size_t)M * E;              // [B,E,S]
    u16* sb  = vbT + (size_t)M * E;              // [B,S,S]

    cvt_all<<<11264, 256, 0, stream>>>(x, Wq, Wk, Wv, xb, wb);

    dim3 blk(256);
    gemm_bt<0><<<dim3(3 * E / BN, M / BM, 1), blk, 0, stream>>>(
        xb, wb, bq, bk, bv, qb, kb, vbT, nullptr, M, 3 * E, D, 0, 0, 0, 1.f);
    gemm_bt<2><<<dim3(S / BN, S / BM, B), blk, 0, stream>>>(
        qb, kb, nullptr, nullptr, nullptr, sb, nullptr, nullptr, nullptr,
        S, S, E, (long)S * E, (long)S * E, (long)S * S, 0.03125f);
    softmax_rows<<<M, 256, 0, stream>>>(sb);
    gemm_bt<3><<<dim3(E / BN, S / BM, B), blk, 0, stream>>>(
        sb, vbT, nullptr, nullptr, nullptr, nullptr, nullptr, nullptr, out,
        S, E, S, (long)S * S, (long)E * S, (long)S * E, 1.f);
}

// Round 5
// 268.487 us; speedup vs baseline: 1.0549x; 1.0549x over previous
//
#include <hip/hip_runtime.h>
#include <stdint.h>

typedef unsigned short u16;
typedef __attribute__((ext_vector_type(8))) __bf16 bf16x8;
typedef __attribute__((ext_vector_type(4))) float f32x4;

__device__ __forceinline__ u16 f2bf(float f) {
    union { float f; uint32_t u; } v; v.f = f;
    uint32_t r = (v.u + 0x7FFFu + ((v.u >> 16) & 1u)) >> 16;
    return (u16)r;
}
__device__ __forceinline__ float bf2f(u16 u) {
    union { uint32_t u; float f; } v; v.u = ((uint32_t)u) << 16;
    return v.f;
}

// Wave-local LDS drain: all prior DS ops complete before any later ones issue.
// Needed for the WAR hazard when a per-wave epilogue window is reused across
// passes (round-4 failure: next-pass ds_writes bypassed prior-pass ds_reads).
__device__ __forceinline__ void lds_fence() {
    __asm__ volatile("s_waitcnt lgkmcnt(0)" ::: "memory");
}

#define BM 128
#define BN 128
#define BK 32

// C = A * Bt^T, A [M,K] bf16 rm, Bt [N,K] bf16 rm.
// MODE 0: fused QKV projection, N=3072. Section bn>>10: 0->q(b0,o0), 1->k(b1,o1),
//         2->v(b2) written TRANSPOSED [b,e,s] into o2.
// MODE 2: bf16 out * scale into o0 (scores)
// MODE 3: fp32 out into o3 (attn @ v)
// Epilogues: per-wave multi-pass retile reusing the 16 KB staging LDS (4 KB/wave),
// with a wave-local lgkmcnt(0) fence between passes (WAR protection).
template<int MODE>
__global__ __launch_bounds__(256, 2) void gemm_bt(
    const u16* __restrict__ A, const u16* __restrict__ Bt,
    const float* __restrict__ b0, const float* __restrict__ b1, const float* __restrict__ b2,
    u16* __restrict__ o0, u16* __restrict__ o1, u16* __restrict__ o2,
    float* __restrict__ o3,
    int M, int N, int K, long sA, long sB, long sC, float scale)
{
    __shared__ __align__(16) u16 smem[BM * BK + BN * BK]; // 16 KB staging (+ epilogue reuse)
    u16* As = smem;
    u16* Bs = smem + BM * BK;

    const int t = threadIdx.x;
    const int lane = t & 63;
    const int wave = t >> 6;
    const int wm = (wave & 1) * 64;
    const int wn = (wave >> 1) * 64;
    const int bm = blockIdx.y * BM;
    const int bn = blockIdx.x * BN;
    const long bz = blockIdx.z;
    const u16* Ab = A + bz * sA;
    const u16* Bb = Bt + bz * sB;

    f32x4 acc[4][4];
#pragma unroll
    for (int i = 0; i < 4; ++i)
#pragma unroll
        for (int j = 0; j < 4; ++j)
            acc[i][j] = (f32x4){0.f, 0.f, 0.f, 0.f};

    const int lrow = t >> 2;
    const int lcol = (t & 3) * 8;

    for (int k0 = 0; k0 < K; k0 += BK) {
#pragma unroll
        for (int r = 0; r < 2; ++r) {
            const u16* ga = Ab + (long)(bm + r * 64 + lrow) * K + (k0 + lcol);
            __builtin_amdgcn_global_load_lds(
                (const __attribute__((address_space(1))) void*)ga,
                (__attribute__((address_space(3))) void*)&As[(r * 256 + t) * 8],
                16, 0, 0);
        }
#pragma unroll
        for (int r = 0; r < 2; ++r) {
            const u16* gb = Bb + (long)(bn + r * 64 + lrow) * K + (k0 + lcol);
            __builtin_amdgcn_global_load_lds(
                (const __attribute__((address_space(1))) void*)gb,
                (__attribute__((address_space(3))) void*)&Bs[(r * 256 + t) * 8],
                16, 0, 0);
        }
        __syncthreads();

        const int fm = lane & 15;
        const int fk = (lane >> 4) * 8;
        bf16x8 af[4], bfr[4];
#pragma unroll
        for (int i = 0; i < 4; ++i) {
            af[i]  = *(const bf16x8*)&As[(wm + i * 16 + fm) * BK + fk];
            bfr[i] = *(const bf16x8*)&Bs[(wn + i * 16 + fm) * BK + fk];
        }
#pragma unroll
        for (int i = 0; i < 4; ++i)
#pragma unroll
            for (int j = 0; j < 4; ++j)
                acc[i][j] = __builtin_amdgcn_mfma_f32_16x16x32_bf16(af[i], bfr[j], acc[i][j], 0, 0, 0);
        __syncthreads();
    }

    // C/D layout: col = lane&15, row = (lane>>4)*4 + reg
    const int cm = (lane >> 4) * 4;
    const int cn = lane & 15;
    u16* Ew = smem + wave * 2048; // 4 KB per-wave epilogue window

    if (MODE == 3) {
        // ---- fp32 out (PV): 8 passes of 8 rows, stride 68 floats ----
        float* Fw = (float*)Ew;
#pragma unroll
        for (int p = 0; p < 8; ++p) {
            if (p) lds_fence(); // WAR: prior pass reads must land before overwrite
            const int i = p >> 1;
            const int h = p & 1;
            if ((cm & 8) == (h << 3)) {
#pragma unroll
                for (int j = 0; j < 4; ++j)
#pragma unroll
                    for (int r = 0; r < 4; ++r)
                        Fw[((cm & 7) + r) * 68 + j * 16 + cn] = acc[i][j][r];
            }
#pragma unroll
            for (int it = 0; it < 2; ++it) {
                const int rl = it * 4 + (lane >> 4);
                const int c4 = (lane & 15) * 4;
                const f32x4 w = *(const f32x4*)&Fw[rl * 68 + c4];
                const int gm = bm + wm + i * 16 + h * 8 + rl;
                *(f32x4*)&o3[bz * sC + (long)gm * N + bn + wn + c4] = w;
            }
        }
    } else if (MODE == 0 && (bn >> 10) == 2) {
        // ---- v projection: transposed [b,e,s]; 4 passes of 16 e-rows, stride 72 ----
        float bb[4];
#pragma unroll
        for (int j = 0; j < 4; ++j) bb[j] = b2[(bn & 1023) + wn + j * 16 + cn];
        const int bgi = (bm + wm) >> 11;
        const int sbase = (bm + wm) & 2047;
#pragma unroll
        for (int j = 0; j < 4; ++j) {
            if (j) lds_fence();
#pragma unroll
            for (int i = 0; i < 4; ++i) {
                ushort4 pk;
                pk.x = f2bf(acc[i][j][0] + bb[j]);
                pk.y = f2bf(acc[i][j][1] + bb[j]);
                pk.z = f2bf(acc[i][j][2] + bb[j]);
                pk.w = f2bf(acc[i][j][3] + bb[j]);
                *(ushort4*)&Ew[cn * 72 + i * 16 + cm] = pk; // [e_local][s_local]
            }
#pragma unroll
            for (int it = 0; it < 2; ++it) {
                const int el = it * 8 + (lane >> 3);
                const int s8 = (lane & 7) * 8;
                const uint4 w = *(const uint4*)&Ew[el * 72 + s8];
                const int eg = (bn & 1023) + wn + j * 16 + el;
                *(uint4*)&o2[((((long)bgi << 10) + eg) << 11) + sbase + s8] = w;
            }
        }
    } else {
        // ---- row-major bf16 (q, k, scores): 4 passes of 16 rows, stride 72 ----
        u16* C;
        int Nout, ncol0;
        long cbase;
        const float* bias;
        if (MODE == 2) {
            C = o0; Nout = N; ncol0 = bn; cbase = bz * sC; bias = nullptr;
        } else {
            const int sec = bn >> 10;
            C = sec ? o1 : o0; Nout = 1024; ncol0 = bn & 1023; cbase = 0;
            bias = sec ? b1 : b0;
        }
        float bb[4];
#pragma unroll
        for (int j = 0; j < 4; ++j)
            bb[j] = bias ? bias[ncol0 + wn + j * 16 + cn] : 0.f;
#pragma unroll
        for (int i = 0; i < 4; ++i) {
            if (i) lds_fence();
#pragma unroll
            for (int j = 0; j < 4; ++j) {
                const int col = j * 16 + cn;
#pragma unroll
                for (int r = 0; r < 4; ++r) {
                    float v = acc[i][j][r];
                    v = (MODE == 2) ? v * scale : v + bb[j];
                    Ew[(cm + r) * 72 + col] = f2bf(v);
                }
            }
#pragma unroll
            for (int it = 0; it < 2; ++it) {
                const int rl = it * 8 + (lane >> 3);
                const int c8 = (lane & 7) * 8;
                const uint4 w = *(const uint4*)&Ew[rl * 72 + c8];
                const int gm = bm + wm + i * 16 + rl;
                *(uint4*)&C[cbase + (long)gm * Nout + ncol0 + wn + c8] = w;
            }
        }
    }
}

// fp32 -> bf16 converts: blocks [0,8192) -> x, then 1024 each for Wq/Wk/Wv
__global__ __launch_bounds__(256) void cvt_all(
    const float* __restrict__ x, const float* __restrict__ wq,
    const float* __restrict__ wk, const float* __restrict__ wv,
    u16* __restrict__ xb, u16* __restrict__ wb)
{
    const int b = blockIdx.x;
    const float* src; u16* dst; long base;
    if (b < 8192)       { src = x;  dst = xb;             base = (long)b * 1024; }
    else if (b < 9216)  { src = wq; dst = wb;             base = (long)(b - 8192) * 1024; }
    else if (b < 10240) { src = wk; dst = wb + (1 << 20); base = (long)(b - 9216) * 1024; }
    else                { src = wv; dst = wb + (2 << 20); base = (long)(b - 10240) * 1024; }
    const long i = base + threadIdx.x * 4;
    const f32x4 f = *(const f32x4*)(src + i);
    ushort4 o;
    o.x = f2bf(f[0]); o.y = f2bf(f[1]); o.z = f2bf(f[2]); o.w = f2bf(f[3]);
    *(ushort4*)(dst + i) = o;
}

// One block per row, 256 threads, 2048 cols, in-place bf16 softmax.
__global__ __launch_bounds__(256) void softmax_rows(u16* __restrict__ S) {
    const long base = (long)blockIdx.x * 2048;
    const int t = threadIdx.x;
    const int lane = t & 63, wave = t >> 6;
    __shared__ float red[4];
    float v[8];
    float m = -3.0e38f;
#pragma unroll
    for (int i = 0; i < 8; ++i) {
        v[i] = bf2f(S[base + t + i * 256]);
        m = fmaxf(m, v[i]);
    }
#pragma unroll
    for (int off = 32; off > 0; off >>= 1) m = fmaxf(m, __shfl_down(m, off));
    if (lane == 0) red[wave] = m;
    __syncthreads();
    m = fmaxf(fmaxf(red[0], red[1]), fmaxf(red[2], red[3]));
    __syncthreads();
    float sum = 0.f;
#pragma unroll
    for (int i = 0; i < 8; ++i) { v[i] = __expf(v[i] - m); sum += v[i]; }
#pragma unroll
    for (int off = 32; off > 0; off >>= 1) sum += __shfl_down(sum, off);
    if (lane == 0) red[wave] = sum;
    __syncthreads();
    sum = red[0] + red[1] + red[2] + red[3];
    const float inv = 1.0f / sum;
#pragma unroll
    for (int i = 0; i < 8; ++i) S[base + t + i * 256] = f2bf(v[i] * inv);
}

extern "C" void kernel_launch(void* const* d_in, const int* in_sizes, int n_in,
                              void* d_out, int out_size, void* d_ws, size_t ws_size,
                              hipStream_t stream) {
    const float* x  = (const float*)d_in[0];
    const float* Wq = (const float*)d_in[1];
    const float* bq = (const float*)d_in[2];
    const float* Wk = (const float*)d_in[3];
    const float* bk = (const float*)d_in[4];
    const float* Wv = (const float*)d_in[5];
    const float* bv = (const float*)d_in[6];
    float* out = (float*)d_out;

    const int B = 4, S = 2048, D = 1024, E = 1024;
    const int M = B * S; // 8192

    u16* xb  = (u16*)d_ws;                       // [M,D]
    u16* wb  = xb  + (size_t)M * D;              // [3E,D] concat Wq,Wk,Wv
    u16* qb  = wb  + (size_t)3 * E * D;          // [M,E]
    u16* kb  = qb  + (size_t)M * E;              // [M,E]
    u16* vbT = kb  + (size_t)M * E;              // [B,E,S]
    u16* sb  = vbT + (size_t)M * E;              // [B,S,S]

    cvt_all<<<11264, 256, 0, stream>>>(x, Wq, Wk, Wv, xb, wb);

    dim3 blk(256);
    gemm_bt<0><<<dim3(3 * E / BN, M / BM, 1), blk, 0, stream>>>(
        xb, wb, bq, bk, bv, qb, kb, vbT, nullptr, M, 3 * E, D, 0, 0, 0, 1.f);
    gemm_bt<2><<<dim3(S / BN, S / BM, B), blk, 0, stream>>>(
        qb, kb, nullptr, nullptr, nullptr, sb, nullptr, nullptr, nullptr,
        S, S, E, (long)S * E, (long)S * E, (long)S * S, 0.03125f);
    softmax_rows<<<M, 256, 0, stream>>>(sb);
    gemm_bt<3><<<dim3(E / BN, S / BM, B), blk, 0, stream>>>(
        sb, vbT, nullptr, nullptr, nullptr, nullptr, nullptr, nullptr, out,
        S, E, S, (long)S * S, (long)E * S, (long)S * E, 1.f);
}

// Round 6
// 260.304 us; speedup vs baseline: 1.0881x; 1.0314x over previous
//
#include <hip/hip_runtime.h>
#include <stdint.h>

typedef unsigned short u16;
typedef __attribute__((ext_vector_type(8))) __bf16 bf16x8;
typedef __attribute__((ext_vector_type(4))) float f32x4;

__device__ __forceinline__ u16 f2bf(float f) {
    union { float f; uint32_t u; } v; v.f = f;
    uint32_t r = (v.u + 0x7FFFu + ((v.u >> 16) & 1u)) >> 16;
    return (u16)r;
}

// Wave-local LDS drain (WAR protection for multi-pass epilogue window reuse).
__device__ __forceinline__ void lds_fence() {
    __asm__ volatile("s_waitcnt lgkmcnt(0)" ::: "memory");
}

#define BM 128
#define BN 128
#define BK 32

// C = A * Bt^T, A [M,K] bf16 rm, Bt [N,K] bf16 rm.
// MODE 0 (PRIV=1): fused QKV projection, N=3072. Section bn>>10: 0->q(b0,o0),
//         1->k(b1,o1), 2->v(b2) TRANSPOSED [b,e,s] into o2. Private 36KB epi, no fences.
// MODE 2 (PRIV=0): exp(s*scale) bf16 into o0 (unnormalized softmax numerator) +
//         atomic per-row sums into lsum. Fenced 4KB/wave retile in staging LDS.
// MODE 3 (PRIV=0): fp32 out = acc / lsum[row] into o3 (attn @ v, normalized).
template<int MODE, int PRIV>
__global__ __launch_bounds__(256, 2) void gemm_bt(
    const u16* __restrict__ A, const u16* __restrict__ Bt,
    const float* __restrict__ b0, const float* __restrict__ b1, const float* __restrict__ b2,
    u16* __restrict__ o0, u16* __restrict__ o1, u16* __restrict__ o2,
    float* __restrict__ o3, float* __restrict__ lsum,
    int M, int N, int K, long sA, long sB, long sC, float scale)
{
    __shared__ __align__(16) u16 smem[BM * BK + BN * BK]; // 16 KB staging
    __shared__ __align__(16) u16 epi[PRIV ? 4 * 64 * 72 : 4]; // 36 KB when PRIV
    u16* As = smem;
    u16* Bs = smem + BM * BK;

    const int t = threadIdx.x;
    const int lane = t & 63;
    const int wave = t >> 6;
    const int wm = (wave & 1) * 64;
    const int wn = (wave >> 1) * 64;
    const int bm = blockIdx.y * BM;
    const int bn = blockIdx.x * BN;
    const long bz = blockIdx.z;
    const u16* Ab = A + bz * sA;
    const u16* Bb = Bt + bz * sB;

    f32x4 acc[4][4];
#pragma unroll
    for (int i = 0; i < 4; ++i)
#pragma unroll
        for (int j = 0; j < 4; ++j)
            acc[i][j] = (f32x4){0.f, 0.f, 0.f, 0.f};

    const int lrow = t >> 2;
    const int lcol = (t & 3) * 8;

    for (int k0 = 0; k0 < K; k0 += BK) {
#pragma unroll
        for (int r = 0; r < 2; ++r) {
            const u16* ga = Ab + (long)(bm + r * 64 + lrow) * K + (k0 + lcol);
            __builtin_amdgcn_global_load_lds(
                (const __attribute__((address_space(1))) void*)ga,
                (__attribute__((address_space(3))) void*)&As[(r * 256 + t) * 8],
                16, 0, 0);
        }
#pragma unroll
        for (int r = 0; r < 2; ++r) {
            const u16* gb = Bb + (long)(bn + r * 64 + lrow) * K + (k0 + lcol);
            __builtin_amdgcn_global_load_lds(
                (const __attribute__((address_space(1))) void*)gb,
                (__attribute__((address_space(3))) void*)&Bs[(r * 256 + t) * 8],
                16, 0, 0);
        }
        __syncthreads();

        const int fm = lane & 15;
        const int fk = (lane >> 4) * 8;
        bf16x8 af[4], bfr[4];
#pragma unroll
        for (int i = 0; i < 4; ++i) {
            af[i]  = *(const bf16x8*)&As[(wm + i * 16 + fm) * BK + fk];
            bfr[i] = *(const bf16x8*)&Bs[(wn + i * 16 + fm) * BK + fk];
        }
#pragma unroll
        for (int i = 0; i < 4; ++i)
#pragma unroll
            for (int j = 0; j < 4; ++j)
                acc[i][j] = __builtin_amdgcn_mfma_f32_16x16x32_bf16(af[i], bfr[j], acc[i][j], 0, 0, 0);
        __syncthreads();
    }

    // C/D layout: col = lane&15, row = (lane>>4)*4 + reg
    const int cm = (lane >> 4) * 4;
    const int cn = lane & 15;
    u16* Ew = PRIV ? (epi + wave * (64 * 72)) : (smem + wave * 2048);

    if (MODE == 3) {
        // ---- fp32 out (PV), normalized by 1/lsum[row]: 8 fenced passes of 8 rows ----
        float* Fw = (float*)Ew;
#pragma unroll
        for (int p = 0; p < 8; ++p) {
            if (p) lds_fence();
            const int i = p >> 1;
            const int h = p & 1;
            if ((cm & 8) == (h << 3)) {
#pragma unroll
                for (int j = 0; j < 4; ++j)
#pragma unroll
                    for (int r = 0; r < 4; ++r)
                        Fw[((cm & 7) + r) * 68 + j * 16 + cn] = acc[i][j][r];
            }
#pragma unroll
            for (int it = 0; it < 2; ++it) {
                const int rl = it * 4 + (lane >> 4);
                const int c4 = (lane & 15) * 4;
                f32x4 w = *(const f32x4*)&Fw[rl * 68 + c4];
                const int gm = bm + wm + i * 16 + h * 8 + rl;
                const float inv = __builtin_amdgcn_rcpf(lsum[bz * 2048 + gm]);
                w[0] *= inv; w[1] *= inv; w[2] *= inv; w[3] *= inv;
                *(f32x4*)&o3[bz * sC + (long)gm * N + bn + wn + c4] = w;
            }
        }
    } else if (MODE == 0 && (bn >> 10) == 2) {
        // ---- v projection: transposed [b,e,s]; private epi, single-shot ----
        float bb[4];
#pragma unroll
        for (int j = 0; j < 4; ++j) bb[j] = b2[(bn & 1023) + wn + j * 16 + cn];
        const int bgi = (bm + wm) >> 11;
        const int sbase = (bm + wm) & 2047;
#pragma unroll
        for (int i = 0; i < 4; ++i)
#pragma unroll
            for (int j = 0; j < 4; ++j) {
                ushort4 pk;
                pk.x = f2bf(acc[i][j][0] + bb[j]);
                pk.y = f2bf(acc[i][j][1] + bb[j]);
                pk.z = f2bf(acc[i][j][2] + bb[j]);
                pk.w = f2bf(acc[i][j][3] + bb[j]);
                *(ushort4*)&Ew[(j * 16 + cn) * 72 + i * 16 + cm] = pk; // [e][s]
            }
#pragma unroll
        for (int it = 0; it < 8; ++it) {
            const int e = it * 8 + (lane >> 3);
            const int s8 = (lane & 7) * 8;
            const uint4 w = *(const uint4*)&Ew[e * 72 + s8];
            const int eg = (bn & 1023) + wn + e;
            *(uint4*)&o2[((((long)bgi << 10) + eg) << 11) + sbase + s8] = w;
        }
    } else if (MODE == 0) {
        // ---- q/k projection, row-major bf16, private epi, single-shot ----
        const int sec = bn >> 10;
        u16* C = sec ? o1 : o0;
        const float* bias = sec ? b1 : b0;
        const int ncol0 = bn & 1023;
        float bb[4];
#pragma unroll
        for (int j = 0; j < 4; ++j) bb[j] = bias[ncol0 + wn + j * 16 + cn];
#pragma unroll
        for (int i = 0; i < 4; ++i)
#pragma unroll
            for (int j = 0; j < 4; ++j) {
                const int col = j * 16 + cn;
#pragma unroll
                for (int r = 0; r < 4; ++r)
                    Ew[(i * 16 + cm + r) * 72 + col] = f2bf(acc[i][j][r] + bb[j]);
            }
#pragma unroll
        for (int it = 0; it < 8; ++it) {
            const int row = it * 8 + (lane >> 3);
            const int c8 = (lane & 7) * 8;
            const uint4 w = *(const uint4*)&Ew[row * 72 + c8];
            const int gm = bm + wm + row;
            *(uint4*)&C[(long)gm * 1024 + ncol0 + wn + c8] = w;
        }
    } else {
        // ---- MODE 2: scores -> exp(s*scale), row-sum atomics, fenced bf16 retile ----
#pragma unroll
        for (int i = 0; i < 4; ++i)
#pragma unroll
            for (int j = 0; j < 4; ++j)
#pragma unroll
                for (int r = 0; r < 4; ++r)
                    acc[i][j][r] = __expf(acc[i][j][r] * scale);
        // per-row partial sums over this block's 128 cols -> atomic into lsum
#pragma unroll
        for (int i = 0; i < 4; ++i) {
#pragma unroll
            for (int r = 0; r < 4; ++r) {
                float s = acc[i][0][r] + acc[i][1][r] + acc[i][2][r] + acc[i][3][r];
                s += __shfl_xor(s, 1);
                s += __shfl_xor(s, 2);
                s += __shfl_xor(s, 4);
                s += __shfl_xor(s, 8);
                if (cn == 0)
                    atomicAdd(&lsum[bz * 2048 + bm + wm + i * 16 + cm + r], s);
            }
        }
#pragma unroll
        for (int i = 0; i < 4; ++i) {
            if (i) lds_fence();
#pragma unroll
            for (int j = 0; j < 4; ++j) {
                const int col = j * 16 + cn;
#pragma unroll
                for (int r = 0; r < 4; ++r)
                    Ew[(cm + r) * 72 + col] = f2bf(acc[i][j][r]);
            }
#pragma unroll
            for (int it = 0; it < 2; ++it) {
                const int rl = it * 8 + (lane >> 3);
                const int c8 = (lane & 7) * 8;
                const uint4 w = *(const uint4*)&Ew[rl * 72 + c8];
                const int gm = bm + wm + i * 16 + rl;
                *(uint4*)&o0[bz * sC + (long)gm * N + bn + wn + c8] = w;
            }
        }
    }
}

// fp32 -> bf16 converts + lsum zeroing.
// blocks [0,8192): x; [8192,9216): Wq; [9216,10240): Wk; [10240,11264): Wv;
// [11264,11272): zero lsum (8192 floats).
__global__ __launch_bounds__(256) void cvt_all(
    const float* __restrict__ x, const float* __restrict__ wq,
    const float* __restrict__ wk, const float* __restrict__ wv,
    u16* __restrict__ xb, u16* __restrict__ wb, float* __restrict__ lsum)
{
    const int b = blockIdx.x;
    if (b >= 11264) {
        const long i = (long)(b - 11264) * 1024 + threadIdx.x * 4;
        *(f32x4*)(lsum + i) = (f32x4){0.f, 0.f, 0.f, 0.f};
        return;
    }
    const float* src; u16* dst; long base;
    if (b < 8192)       { src = x;  dst = xb;             base = (long)b * 1024; }
    else if (b < 9216)  { src = wq; dst = wb;             base = (long)(b - 8192) * 1024; }
    else if (b < 10240) { src = wk; dst = wb + (1 << 20); base = (long)(b - 9216) * 1024; }
    else                { src = wv; dst = wb + (2 << 20); base = (long)(b - 10240) * 1024; }
    const long i = base + threadIdx.x * 4;
    const f32x4 f = *(const f32x4*)(src + i);
    ushort4 o;
    o.x = f2bf(f[0]); o.y = f2bf(f[1]); o.z = f2bf(f[2]); o.w = f2bf(f[3]);
    *(ushort4*)(dst + i) = o;
}

extern "C" void kernel_launch(void* const* d_in, const int* in_sizes, int n_in,
                              void* d_out, int out_size, void* d_ws, size_t ws_size,
                              hipStream_t stream) {
    const float* x  = (const float*)d_in[0];
    const float* Wq = (const float*)d_in[1];
    const float* bq = (const float*)d_in[2];
    const float* Wk = (const float*)d_in[3];
    const float* bk = (const float*)d_in[4];
    const float* Wv = (const float*)d_in[5];
    const float* bv = (const float*)d_in[6];
    float* out = (float*)d_out;

    const int B = 4, S = 2048, D = 1024, E = 1024;
    const int M = B * S; // 8192

    u16* xb  = (u16*)d_ws;                       // [M,D]
    u16* wb  = xb  + (size_t)M * D;              // [3E,D]
    u16* qb  = wb  + (size_t)3 * E * D;          // [M,E]
    u16* kb  = qb  + (size_t)M * E;              // [M,E]
    u16* vbT = kb  + (size_t)M * E;              // [B,E,S]
    u16* sb  = vbT + (size_t)M * E;              // [B,S,S] exp-scores
    float* lsum = (float*)(sb + (size_t)M * S);  // [M] row sums

    cvt_all<<<11272, 256, 0, stream>>>(x, Wq, Wk, Wv, xb, wb, lsum);

    dim3 blk(256);
    // fused QKV projection (private 36KB epilogue)
    gemm_bt<0, 1><<<dim3(3 * E / BN, M / BM, 1), blk, 0, stream>>>(
        xb, wb, bq, bk, bv, qb, kb, vbT, nullptr, nullptr, M, 3 * E, D, 0, 0, 0, 1.f);
    // exp-scores + row sums
    gemm_bt<2, 0><<<dim3(S / BN, S / BM, B), blk, 0, stream>>>(
        qb, kb, nullptr, nullptr, nullptr, sb, nullptr, nullptr, nullptr, lsum,
        S, S, E, (long)S * E, (long)S * E, (long)S * S, 0.03125f);
    // out = (expS @ v) / lsum
    gemm_bt<3, 0><<<dim3(E / BN, S / BM, B), blk, 0, stream>>>(
        sb, vbT, nullptr, nullptr, nullptr, nullptr, nullptr, nullptr, out, lsum,
        S, E, S, (long)S * S, (long)E * S, (long)S * E, 1.f);
}

// Round 7
// 241.766 us; speedup vs baseline: 1.1715x; 1.0767x over previous
//
#include <hip/hip_runtime.h>
#include <stdint.h>

typedef unsigned short u16;
typedef __attribute__((ext_vector_type(8))) __bf16 bf16x8;
typedef __attribute__((ext_vector_type(4))) float f32x4;

__device__ __forceinline__ u16 f2bf(float f) {
    union { float f; uint32_t u; } v; v.f = f;
    uint32_t r = (v.u + 0x7FFFu + ((v.u >> 16) & 1u)) >> 16;
    return (u16)r;
}

// Wave-local LDS drain (WAR protection when a window is rewritten).
__device__ __forceinline__ void lds_fence() {
    __asm__ volatile("s_waitcnt lgkmcnt(0)" ::: "memory");
}

#define BM 128
#define BN 128
#define BK 64   // staged as two [128][32] halves (keeps m97 bank profile; half the barriers)

// C = A * Bt^T, A [M,K] bf16 rm, Bt [N,K] bf16 rm. K % 64 == 0.
// MODE 0: fused QKV projection, N=3072. Section bn>>10: 0->q(b0,o0), 1->k(b1,o1),
//         2->v(b2) TRANSPOSED [b,e,s] into o2.
// MODE 2: exp(s*scale) bf16 into o0 + atomic per-row sums into lsum.
// MODE 3: fp32 out = acc / lsum[row] into o3.
// LDS: 36 KB union — 32 KB staging (4 sub-tiles) during K-loop; after the final
// __syncthreads the same block provides 9216 B per-wave epilogue windows
// (single-shot write->read, no fences; PV: 2 passes + 1 fence).
template<int MODE>
__global__ __launch_bounds__(256, 4) void gemm_bt(
    const u16* __restrict__ A, const u16* __restrict__ Bt,
    const float* __restrict__ b0, const float* __restrict__ b1, const float* __restrict__ b2,
    u16* __restrict__ o0, u16* __restrict__ o1, u16* __restrict__ o2,
    float* __restrict__ o3, float* __restrict__ lsum,
    int M, int N, int K, long sA, long sB, long sC, float scale)
{
    __shared__ __align__(16) u16 smem[4 * 64 * 72]; // 36864 B
    // staging views: A half0 @0, A half1 @4096, B half0 @8192, B half1 @12288 (u16 idx)

    const int t = threadIdx.x;
    const int lane = t & 63;
    const int wave = t >> 6;
    const int wm = (wave & 1) * 64;
    const int wn = (wave >> 1) * 64;
    const int bm = blockIdx.y * BM;
    const int bn = blockIdx.x * BN;
    const long bz = blockIdx.z;
    const u16* Ab = A + bz * sA;
    const u16* Bb = Bt + bz * sB;

    f32x4 acc[4][4];
#pragma unroll
    for (int i = 0; i < 4; ++i)
#pragma unroll
        for (int j = 0; j < 4; ++j)
            acc[i][j] = (f32x4){0.f, 0.f, 0.f, 0.f};

    const int lrow = t >> 2;          // 0..63
    const int lcol = (t & 3) * 8;     // 0,8,16,24 (within a 32-col half)
    const int fm = lane & 15;
    const int fk = (lane >> 4) * 8;

    for (int k0 = 0; k0 < K; k0 += BK) {
#pragma unroll
        for (int h = 0; h < 2; ++h)
#pragma unroll
            for (int r = 0; r < 2; ++r) {
                const u16* ga = Ab + (long)(bm + r * 64 + lrow) * K + (k0 + h * 32 + lcol);
                __builtin_amdgcn_global_load_lds(
                    (const __attribute__((address_space(1))) void*)ga,
                    (__attribute__((address_space(3))) void*)&smem[h * 4096 + (r * 256 + t) * 8],
                    16, 0, 0);
            }
#pragma unroll
        for (int h = 0; h < 2; ++h)
#pragma unroll
            for (int r = 0; r < 2; ++r) {
                const u16* gb = Bb + (long)(bn + r * 64 + lrow) * K + (k0 + h * 32 + lcol);
                __builtin_amdgcn_global_load_lds(
                    (const __attribute__((address_space(1))) void*)gb,
                    (__attribute__((address_space(3))) void*)&smem[8192 + h * 4096 + (r * 256 + t) * 8],
                    16, 0, 0);
            }
        __syncthreads();

#pragma unroll
        for (int h = 0; h < 2; ++h) {
            bf16x8 af[4], bfr[4];
#pragma unroll
            for (int i = 0; i < 4; ++i) {
                af[i]  = *(const bf16x8*)&smem[h * 4096 + (wm + i * 16 + fm) * 32 + fk];
                bfr[i] = *(const bf16x8*)&smem[8192 + h * 4096 + (wn + i * 16 + fm) * 32 + fk];
            }
#pragma unroll
            for (int i = 0; i < 4; ++i)
#pragma unroll
                for (int j = 0; j < 4; ++j)
                    acc[i][j] = __builtin_amdgcn_mfma_f32_16x16x32_bf16(af[i], bfr[j], acc[i][j], 0, 0, 0);
        }
        __syncthreads();
    }

    // C/D layout: col = lane&15, row = (lane>>4)*4 + reg
    const int cm = (lane >> 4) * 4;
    const int cn = lane & 15;
    u16* Ew = smem + wave * 4608; // 9216 B per-wave window (16B aligned)

    if (MODE == 3) {
        // ---- fp32 out (PV), /lsum[row]: 2 passes of 32 rows, stride 68 fp32 ----
        float* Fw = (float*)Ew; // needs 32*68*4 = 8704 B <= 9216
#pragma unroll
        for (int p = 0; p < 2; ++p) {
            if (p) lds_fence();
#pragma unroll
            for (int ii = 0; ii < 2; ++ii) {
                const int i = p * 2 + ii;
#pragma unroll
                for (int j = 0; j < 4; ++j)
#pragma unroll
                    for (int r = 0; r < 4; ++r)
                        Fw[(ii * 16 + cm + r) * 68 + j * 16 + cn] = acc[i][j][r];
            }
#pragma unroll
            for (int it = 0; it < 8; ++it) {
                const int row = it * 4 + (lane >> 4);
                const int c4 = (lane & 15) * 4;
                f32x4 w = *(const f32x4*)&Fw[row * 68 + c4];
                const int gm = bm + wm + p * 32 + row;
                const float inv = __builtin_amdgcn_rcpf(lsum[bz * 2048 + gm]);
                w[0] *= inv; w[1] *= inv; w[2] *= inv; w[3] *= inv;
                *(f32x4*)&o3[bz * sC + (long)gm * N + bn + wn + c4] = w;
            }
        }
    } else if (MODE == 0 && (bn >> 10) == 2) {
        // ---- v projection: transposed [b,e,s]; single-shot ----
        float bb[4];
#pragma unroll
        for (int j = 0; j < 4; ++j) bb[j] = b2[(bn & 1023) + wn + j * 16 + cn];
        const int bgi = (bm + wm) >> 11;
        const int sbase = (bm + wm) & 2047;
#pragma unroll
        for (int i = 0; i < 4; ++i)
#pragma unroll
            for (int j = 0; j < 4; ++j) {
                ushort4 pk;
                pk.x = f2bf(acc[i][j][0] + bb[j]);
                pk.y = f2bf(acc[i][j][1] + bb[j]);
                pk.z = f2bf(acc[i][j][2] + bb[j]);
                pk.w = f2bf(acc[i][j][3] + bb[j]);
                *(ushort4*)&Ew[(j * 16 + cn) * 72 + i * 16 + cm] = pk; // [e][s]
            }
#pragma unroll
        for (int it = 0; it < 8; ++it) {
            const int e = it * 8 + (lane >> 3);
            const int s8 = (lane & 7) * 8;
            const uint4 w = *(const uint4*)&Ew[e * 72 + s8];
            const int eg = (bn & 1023) + wn + e;
            *(uint4*)&o2[((((long)bgi << 10) + eg) << 11) + sbase + s8] = w;
        }
    } else if (MODE == 0) {
        // ---- q/k projection, row-major bf16, single-shot ----
        const int sec = bn >> 10;
        u16* C = sec ? o1 : o0;
        const float* bias = sec ? b1 : b0;
        const int ncol0 = bn & 1023;
        float bb[4];
#pragma unroll
        for (int j = 0; j < 4; ++j) bb[j] = bias[ncol0 + wn + j * 16 + cn];
#pragma unroll
        for (int i = 0; i < 4; ++i)
#pragma unroll
            for (int j = 0; j < 4; ++j) {
                const int col = j * 16 + cn;
#pragma unroll
                for (int r = 0; r < 4; ++r)
                    Ew[(i * 16 + cm + r) * 72 + col] = f2bf(acc[i][j][r] + bb[j]);
            }
#pragma unroll
        for (int it = 0; it < 8; ++it) {
            const int row = it * 8 + (lane >> 3);
            const int c8 = (lane & 7) * 8;
            const uint4 w = *(const uint4*)&Ew[row * 72 + c8];
            const int gm = bm + wm + row;
            *(uint4*)&C[(long)gm * 1024 + ncol0 + wn + c8] = w;
        }
    } else {
        // ---- MODE 2: exp(s*scale), row-sum atomics, single-shot bf16 retile ----
#pragma unroll
        for (int i = 0; i < 4; ++i)
#pragma unroll
            for (int j = 0; j < 4; ++j)
#pragma unroll
                for (int r = 0; r < 4; ++r)
                    acc[i][j][r] = __expf(acc[i][j][r] * scale);
#pragma unroll
        for (int i = 0; i < 4; ++i) {
#pragma unroll
            for (int r = 0; r < 4; ++r) {
                float s = acc[i][0][r] + acc[i][1][r] + acc[i][2][r] + acc[i][3][r];
                s += __shfl_xor(s, 1);
                s += __shfl_xor(s, 2);
                s += __shfl_xor(s, 4);
                s += __shfl_xor(s, 8);
                if (cn == 0)
                    atomicAdd(&lsum[bz * 2048 + bm + wm + i * 16 + cm + r], s);
            }
        }
#pragma unroll
        for (int i = 0; i < 4; ++i)
#pragma unroll
            for (int j = 0; j < 4; ++j) {
                const int col = j * 16 + cn;
#pragma unroll
                for (int r = 0; r < 4; ++r)
                    Ew[(i * 16 + cm + r) * 72 + col] = f2bf(acc[i][j][r]);
            }
#pragma unroll
        for (int it = 0; it < 8; ++it) {
            const int row = it * 8 + (lane >> 3);
            const int c8 = (lane & 7) * 8;
            const uint4 w = *(const uint4*)&Ew[row * 72 + c8];
            const int gm = bm + wm + row;
            *(uint4*)&o0[bz * sC + (long)gm * N + bn + wn + c8] = w;
        }
    }
}

// fp32 -> bf16 converts + lsum zeroing.
__global__ __launch_bounds__(256) void cvt_all(
    const float* __restrict__ x, const float* __restrict__ wq,
    const float* __restrict__ wk, const float* __restrict__ wv,
    u16* __restrict__ xb, u16* __restrict__ wb, float* __restrict__ lsum)
{
    const int b = blockIdx.x;
    if (b >= 11264) {
        const long i = (long)(b - 11264) * 1024 + threadIdx.x * 4;
        *(f32x4*)(lsum + i) = (f32x4){0.f, 0.f, 0.f, 0.f};
        return;
    }
    const float* src; u16* dst; long base;
    if (b < 8192)       { src = x;  dst = xb;             base = (long)b * 1024; }
    else if (b < 9216)  { src = wq; dst = wb;             base = (long)(b - 8192) * 1024; }
    else if (b < 10240) { src = wk; dst = wb + (1 << 20); base = (long)(b - 9216) * 1024; }
    else                { src = wv; dst = wb + (2 << 20); base = (long)(b - 10240) * 1024; }
    const long i = base + threadIdx.x * 4;
    const f32x4 f = *(const f32x4*)(src + i);
    ushort4 o;
    o.x = f2bf(f[0]); o.y = f2bf(f[1]); o.z = f2bf(f[2]); o.w = f2bf(f[3]);
    *(ushort4*)(dst + i) = o;
}

extern "C" void kernel_launch(void* const* d_in, const int* in_sizes, int n_in,
                              void* d_out, int out_size, void* d_ws, size_t ws_size,
                              hipStream_t stream) {
    const float* x  = (const float*)d_in[0];
    const float* Wq = (const float*)d_in[1];
    const float* bq = (const float*)d_in[2];
    const float* Wk = (const float*)d_in[3];
    const float* bk = (const float*)d_in[4];
    const float* Wv = (const float*)d_in[5];
    const float* bv = (const float*)d_in[6];
    float* out = (float*)d_out;

    const int B = 4, S = 2048, D = 1024, E = 1024;
    const int M = B * S; // 8192

    u16* xb  = (u16*)d_ws;                       // [M,D]
    u16* wb  = xb  + (size_t)M * D;              // [3E,D]
    u16* qb  = wb  + (size_t)3 * E * D;          // [M,E]
    u16* kb  = qb  + (size_t)M * E;              // [M,E]
    u16* vbT = kb  + (size_t)M * E;              // [B,E,S]
    u16* sb  = vbT + (size_t)M * E;              // [B,S,S] exp-scores
    float* lsum = (float*)(sb + (size_t)M * S);  // [M]

    cvt_all<<<11272, 256, 0, stream>>>(x, Wq, Wk, Wv, xb, wb, lsum);

    dim3 blk(256);
    gemm_bt<0><<<dim3(3 * E / BN, M / BM, 1), blk, 0, stream>>>(
        xb, wb, bq, bk, bv, qb, kb, vbT, nullptr, nullptr, M, 3 * E, D, 0, 0, 0, 1.f);
    gemm_bt<2><<<dim3(S / BN, S / BM, B), blk, 0, stream>>>(
        qb, kb, nullptr, nullptr, nullptr, sb, nullptr, nullptr, nullptr, lsum,
        S, S, E, (long)S * E, (long)S * E, (long)S * S, 0.03125f);
    gemm_bt<3><<<dim3(E / BN, S / BM, B), blk, 0, stream>>>(
        sb, vbT, nullptr, nullptr, nullptr, nullptr, nullptr, nullptr, out, lsum,
        S, E, S, (long)S * S, (long)E * S, (long)S * E, 1.f);
}